// Round 2
// baseline (1073.597 us; speedup 1.0000x reference)
//
#include <hip/hip_runtime.h>

#define N_NODES 100000
#define N_EDGES 1000000
#define N_GRAPHS 128

// ---------------------------------------------------------------------------
// Edge phase: one wave (64 lanes) per edge, SCALAR edge loop.
// e0 = readfirstlane(wid) makes the edge index SGPR-uniform, so src[e],
// dst[e] and the whole 128B ea row become uniform (scalar-cache) loads and
// the 32 FMAs use scalar operands — no shuffles at all.
//   e_i = sum_k ea[e][k] * We[k][i] + be[i]
//   m_i = relu(x[src][i] + e_i);  atomicAdd(aggr[dst][i], m_i)
// ---------------------------------------------------------------------------
__global__ __launch_bounds__(256) void edge_kernel(
    const float* __restrict__ x,     // [N,64] conv input
    const float* __restrict__ ea,    // [E,32]
    const int*   __restrict__ src,   // [E]
    const int*   __restrict__ dst,   // [E]
    const float* __restrict__ We,    // [32,64]
    const float* __restrict__ be,    // [64]
    float*       __restrict__ aggr)  // [N,64], pre-zeroed
{
    const int lane = threadIdx.x & 63;
    const int wid  = (blockIdx.x * blockDim.x + threadIdx.x) >> 6;
    const int nw   = (gridDim.x * blockDim.x) >> 6;

    float w[32];
#pragma unroll
    for (int k = 0; k < 32; ++k) w[k] = We[k * 64 + lane];
    const float b = be[lane];

    // wave-uniform loop bounds -> scalar loop, scalar loads
    const int e0 = __builtin_amdgcn_readfirstlane(wid);
    for (int e = e0; e < N_EDGES; e += nw) {
        const int s = src[e];            // uniform -> s_load
        const int d = dst[e];            // uniform -> s_load
        const float* earow = ea + (size_t)e * 32;  // uniform 128B row

        const float xv = x[(size_t)s * 64 + lane]; // coalesced vector load

        float acc = b;
#pragma unroll
        for (int k = 0; k < 32; ++k)
            acc = fmaf(earow[k], w[k], acc);       // scalar * vgpr fma

        const float m = fmaxf(xv + acc, 0.0f);
        atomicAdd(&aggr[(size_t)d * 64 + lane], m);
    }
}

// ---------------------------------------------------------------------------
// Node phase: one wave per node, lane i owns feature i.
//   h = (1+eps)*x_in + aggr
//   out = relu( relu(h@W1+b1) @ W2 + b2 )   (outer relu = post-conv relu)
// Both weight matrices' columns live in registers (128 VGPR). Constant-index
// __shfl lowers to v_readlane (scalar broadcast). In-place safe.
// ---------------------------------------------------------------------------
__global__ __launch_bounds__(256) void node_kernel(
    const float* __restrict__ x_in,  // [N,64]
    const float* __restrict__ aggr,  // [N,64]
    const float* __restrict__ eps,   // scalar
    const float* __restrict__ W1,    // [64,64]
    const float* __restrict__ b1,    // [64]
    const float* __restrict__ W2,    // [64,64]
    const float* __restrict__ b2,    // [64]
    float*       __restrict__ h_out) // [N,64]
{
    const int lane = threadIdx.x & 63;
    const int wid  = (blockIdx.x * blockDim.x + threadIdx.x) >> 6;
    const int nw   = (gridDim.x * blockDim.x) >> 6;

    float w1[64], w2[64];
#pragma unroll
    for (int i = 0; i < 64; ++i) w1[i] = W1[i * 64 + lane];
#pragma unroll
    for (int i = 0; i < 64; ++i) w2[i] = W2[i * 64 + lane];
    const float b1v = b1[lane];
    const float b2v = b2[lane];
    const float ep  = 1.0f + eps[0];

    for (int n = wid; n < N_NODES; n += nw) {
        const size_t base = (size_t)n * 64;
        const float h = fmaf(ep, x_in[base + lane], aggr[base + lane]);

        float t = b1v;
#pragma unroll
        for (int i = 0; i < 64; ++i)
            t = fmaf(__shfl(h, i), w1[i], t);
        t = fmaxf(t, 0.0f);

        float o = b2v;
#pragma unroll
        for (int i = 0; i < 64; ++i)
            o = fmaf(__shfl(t, i), w2[i], o);

        h_out[base + lane] = fmaxf(o, 0.0f);
    }
}

// ---------------------------------------------------------------------------
// Pooling: batch is sorted, so each wave reduces a contiguous chunk of nodes
// in registers and emits one atomicAdd per graph-run (~1-2 per chunk).
// ---------------------------------------------------------------------------
#define POOL_CHUNK 128
__global__ __launch_bounds__(256) void pool_kernel(
    const float* __restrict__ h,      // [N,64]
    const int*   __restrict__ batch,  // [N], sorted
    float*       __restrict__ pooled) // [128,64], pre-zeroed
{
    const int lane  = threadIdx.x & 63;
    const int wid   = (blockIdx.x * blockDim.x + threadIdx.x) >> 6;
    const int start = wid * POOL_CHUNK;
    if (start >= N_NODES) return;
    const int end = min(start + POOL_CHUNK, N_NODES);

    int   gcur = batch[start];
    float acc  = 0.0f;
    for (int n = start; n < end; ++n) {
        const int g = batch[n];
        if (g != gcur) {
            atomicAdd(&pooled[gcur * 64 + lane], acc);
            acc  = 0.0f;
            gcur = g;
        }
        acc += h[(size_t)n * 64 + lane];
    }
    atomicAdd(&pooled[gcur * 64 + lane], acc);
}

// ---------------------------------------------------------------------------
// Head: one block (128 threads) per graph.
//   t_j = relu(pooled[g] . Wf1[:,j] + bf1[j]);  out[g] = t . Wf2 + bf2
// ---------------------------------------------------------------------------
__global__ __launch_bounds__(128) void head_kernel(
    const float* __restrict__ pooled, // [128,64]
    const float* __restrict__ Wf1,    // [64,128]
    const float* __restrict__ bf1,    // [128]
    const float* __restrict__ Wf2,    // [128,1]
    const float* __restrict__ bf2,    // [1]
    float*       __restrict__ out)    // [128]
{
    __shared__ float p[64];
    __shared__ float red[2];
    const int g = blockIdx.x;
    const int j = threadIdx.x;

    if (j < 64) p[j] = pooled[g * 64 + j];
    __syncthreads();

    float t = bf1[j];
#pragma unroll
    for (int i = 0; i < 64; ++i)
        t = fmaf(p[i], Wf1[i * 128 + j], t);
    t = fmaxf(t, 0.0f);

    float v = t * Wf2[j];
    for (int off = 32; off > 0; off >>= 1)
        v += __shfl_down(v, off);
    if ((j & 63) == 0) red[j >> 6] = v;
    __syncthreads();
    if (j == 0) out[g] = red[0] + red[1] + bf2[0];
}

extern "C" void kernel_launch(void* const* d_in, const int* in_sizes, int n_in,
                              void* d_out, int out_size, void* d_ws, size_t ws_size,
                              hipStream_t stream) {
    const float* x    = (const float*)d_in[0];
    const float* ea   = (const float*)d_in[1];
    const int*   esrc = (const int*)  d_in[2];
    const int*   edst = (const int*)  d_in[3];
    const int*   batch= (const int*)  d_in[4];
    const float* eps1 = (const float*)d_in[5];
    const float* We1  = (const float*)d_in[6];
    const float* be1  = (const float*)d_in[7];
    const float* W11  = (const float*)d_in[8];
    const float* b11  = (const float*)d_in[9];
    const float* W12  = (const float*)d_in[10];
    const float* b12  = (const float*)d_in[11];
    const float* eps2 = (const float*)d_in[12];
    const float* We2  = (const float*)d_in[13];
    const float* be2  = (const float*)d_in[14];
    const float* W21  = (const float*)d_in[15];
    const float* b21  = (const float*)d_in[16];
    const float* W22  = (const float*)d_in[17];
    const float* b22  = (const float*)d_in[18];
    const float* Wf1  = (const float*)d_in[19];
    const float* bf1  = (const float*)d_in[20];
    const float* Wf2  = (const float*)d_in[21];
    const float* bf2  = (const float*)d_in[22];
    float* out = (float*)d_out;

    const size_t node_feat_bytes = (size_t)N_NODES * 64 * sizeof(float);
    char* ws = (char*)d_ws;
    float* aggr   = (float*)ws;                          // 25.6 MB
    float* h      = (float*)(ws + node_feat_bytes);      // 25.6 MB
    float* pooled = (float*)(ws + 2 * node_feat_bytes);  // 32 KB

    const int EDGE_BLOCKS = 2048;   // 8192 waves
    const int NODE_BLOCKS = 1024;   // 4096 waves
    const int POOL_WAVES  = (N_NODES + POOL_CHUNK - 1) / POOL_CHUNK;  // 782
    const int POOL_BLOCKS = (POOL_WAVES + 3) / 4;

    // ---- conv1 ----
    hipMemsetAsync(aggr, 0, node_feat_bytes, stream);
    edge_kernel<<<EDGE_BLOCKS, 256, 0, stream>>>(x, ea, esrc, edst, We1, be1, aggr);
    node_kernel<<<NODE_BLOCKS, 256, 0, stream>>>(x, aggr, eps1, W11, b11, W12, b12, h);

    // ---- conv2 ----
    hipMemsetAsync(aggr, 0, node_feat_bytes, stream);
    edge_kernel<<<EDGE_BLOCKS, 256, 0, stream>>>(h, ea, esrc, edst, We2, be2, aggr);
    node_kernel<<<NODE_BLOCKS, 256, 0, stream>>>(h, aggr, eps2, W21, b21, W22, b22, h);

    // ---- global_add_pool ----
    hipMemsetAsync(pooled, 0, (size_t)N_GRAPHS * 64 * sizeof(float), stream);
    pool_kernel<<<POOL_BLOCKS, 256, 0, stream>>>(h, batch, pooled);

    // ---- head MLP ----
    head_kernel<<<N_GRAPHS, 128, 0, stream>>>(pooled, Wf1, bf1, Wf2, bf2, out);
}